// Round 7
// baseline (857.115 us; speedup 1.0000x reference)
//
#include <hip/hip_runtime.h>

#define BATCH 8
#define NPTS 4096
#define NSAMP 512   // npoint = NPTS/8

#define ROW_SHR(n) (0x110 | (n))
#define ROW_BCAST15 0x142
#define ROW_BCAST31 0x143

// one max-combine step on a packed u64 key via DPP (VALU latency, no LDS).
template <int CTRL, int RMASK>
__device__ __forceinline__ unsigned long long kmax_dpp(unsigned long long k) {
  unsigned lo = (unsigned)__builtin_amdgcn_update_dpp(0, (int)(unsigned)k,
                                                      CTRL, RMASK, 0xf, true);
  unsigned hi = (unsigned)__builtin_amdgcn_update_dpp(0, (int)(unsigned)(k >> 32),
                                                      CTRL, RMASK, 0xf, true);
  unsigned long long o = ((unsigned long long)hi << 32) | lo;
  return o > k ? o : k;   // masked/OOB lanes deliver 0 -> identity
}

// ---------------------------------------------------------------------------
// Kernel A: farthest point sampling (r3 version — best measured ~250 us).
// Exact fp32 (no FMA contraction) so argmax selection matches numpy exactly.
// key = (float_bits(val) << 32) | ~idx  => u64-max == (max, tie->smaller idx).
// ---------------------------------------------------------------------------
__global__ __launch_bounds__(256) void fps_kernel(const float* __restrict__ pcd,
                                                  float* __restrict__ new_xyz) {
  __shared__ float4 s_pts[NPTS];                       // 64 KB
  __shared__ unsigned long long red[2][4];             // parity double-buffer

  const int b = blockIdx.x;
  const int t = threadIdx.x;
  const int wave = t >> 6;
  const int lane = t & 63;
  const float* xb = pcd + (size_t)b * NPTS * 3;

  float X[16], Y[16], Z[16], mind[16];
#pragma unroll
  for (int j = 0; j < 16; ++j) {
    int i = t + 256 * j;
    float x = xb[i * 3 + 0], y = xb[i * 3 + 1], z = xb[i * 3 + 2];
    X[j] = x; Y[j] = y; Z[j] = z;
    s_pts[i] = make_float4(x, y, z, 0.0f);
    mind[j] = 10000000000.0f;
  }
  __syncthreads();

  float px = xb[0], py = xb[1], pz = xb[2];            // idx 0 is first sample

  for (int it = 0; it < NSAMP; ++it) {
    if (t == 0) {
      size_t o = ((size_t)b * NSAMP + it) * 3;
      new_xyz[o + 0] = px; new_xyz[o + 1] = py; new_xyz[o + 2] = pz;
    }
    float bv = -1.0f; int bi = 0;
#pragma unroll
    for (int j = 0; j < 16; ++j) {
      float dx = __fsub_rn(X[j], px);
      float dy = __fsub_rn(Y[j], py);
      float dz = __fsub_rn(Z[j], pz);
      float d = __fadd_rn(__fadd_rn(__fmul_rn(dx, dx), __fmul_rn(dy, dy)),
                          __fmul_rn(dz, dz));
      float m = fminf(mind[j], d);
      mind[j] = m;
      if (m > bv) { bv = m; bi = t + 256 * j; }        // strict >: first occ.
    }
    unsigned long long key =
        ((unsigned long long)__float_as_uint(bv) << 32) |
        (unsigned long long)(~(unsigned)bi);
    key = kmax_dpp<ROW_SHR(1), 0xf>(key);
    key = kmax_dpp<ROW_SHR(2), 0xf>(key);
    key = kmax_dpp<ROW_SHR(4), 0xf>(key);
    key = kmax_dpp<ROW_SHR(8), 0xf>(key);
    key = kmax_dpp<ROW_BCAST15, 0xa>(key);
    key = kmax_dpp<ROW_BCAST31, 0xc>(key);
    unsigned wlo = (unsigned)__builtin_amdgcn_readlane((int)(unsigned)key, 63);
    unsigned whi = (unsigned)__builtin_amdgcn_readlane((int)(unsigned)(key >> 32), 63);
    if (lane == 0)
      red[it & 1][wave] = ((unsigned long long)whi << 32) | wlo;
    __syncthreads();
    unsigned long long g = red[it & 1][0];
    unsigned long long g1 = red[it & 1][1];
    unsigned long long g2 = red[it & 1][2];
    unsigned long long g3 = red[it & 1][3];
    if (g1 > g) g = g1;
    if (g2 > g) g = g2;
    if (g3 > g) g = g3;
    int nxt = (int)(~(unsigned)g);
    float4 p = s_pts[nxt];
    px = p.x; py = p.y; pz = p.z;
  }
}

// ---------------------------------------------------------------------------
// Weight prep: transpose each w[cin][cout] into wt[cout][cinp] (cin padded
// to a multiple of 4 with zeros) so MLP threads can float4-load weights.
// ---------------------------------------------------------------------------
__device__ __forceinline__ void tsec(int g, const float* __restrict__ w,
                                     float* __restrict__ wt, int cin, int cinp,
                                     int cout, int base) {
  int local = g - base;
  if (local < 0 || local >= cinp * cout) return;
  int oc = local / cinp, ic = local % cinp;
  wt[base + local] = (ic < cin) ? w[ic * cout + oc] : 0.0f;
}

#define W00 0
#define W01 128
#define W02 1152
#define W10 3200
#define W11 3456
#define W12 7552
#define W20 15744
#define W21 16000
#define W22 22144
#define WT_TOTAL 34432

__global__ __launch_bounds__(256) void prep_kernel(
    const float* w00, const float* w01, const float* w02,
    const float* w10, const float* w11, const float* w12,
    const float* w20, const float* w21, const float* w22,
    float* __restrict__ wt) {
  int g = blockIdx.x * 256 + threadIdx.x;
  tsec(g, w00, wt, 3, 4, 32, W00);
  tsec(g, w01, wt, 32, 32, 32, W01);
  tsec(g, w02, wt, 32, 32, 64, W02);
  tsec(g, w10, wt, 3, 4, 64, W10);
  tsec(g, w11, wt, 64, 64, 64, W11);
  tsec(g, w12, wt, 64, 64, 128, W12);
  tsec(g, w20, wt, 3, 4, 64, W20);
  tsec(g, w21, wt, 64, 64, 96, W21);
  tsec(g, w22, wt, 96, 96, 128, W22);
}

// ---------------------------------------------------------------------------
// MLP building blocks. wtb = weight base already offset to this thread's
// first output row (row stride WS); hin = LDS input (row stride NTPI).
// Accumulation order over input channels is sequential 0..CIN-1 => bitwise
// identical to the reference einsum regardless of how callers split ICs.
// ---------------------------------------------------------------------------
template <int TOC, int TN>
__device__ __forceinline__ void init_bias(float (&acc)[TOC][TN],
                                          const float* bias) {
#pragma unroll
  for (int j = 0; j < TOC; ++j) {
    float bj = bias[j];
#pragma unroll
    for (int i = 0; i < TN; ++i) acc[j][i] = bj;
  }
}

template <int CIN4, int TOC, int TN, int NTPI, int WS>
__device__ __forceinline__ void layer_acc(const float* __restrict__ wtb,
                                          const float* hin,
                                          float (&acc)[TOC][TN], int tn) {
#pragma unroll 2
  for (int c4 = 0; c4 < CIN4; ++c4) {
    float hv[4][TN];
#pragma unroll
    for (int k = 0; k < 4; ++k) {
      const float* src = &hin[(c4 * 4 + k) * NTPI + tn * TN];
      if constexpr (TN == 1) {
        hv[k][0] = src[0];
      } else if constexpr (TN == 2) {
        float2 v = *(const float2*)src; hv[k][0] = v.x; hv[k][1] = v.y;
      } else {
        float4 v = *(const float4*)src;
        hv[k][0] = v.x; hv[k][1] = v.y; hv[k][2] = v.z; hv[k][3] = v.w;
      }
    }
#pragma unroll
    for (int j = 0; j < TOC; ++j) {
      float4 w4 = *(const float4*)&wtb[j * WS + c4 * 4];
#pragma unroll
      for (int i = 0; i < TN; ++i) {
        acc[j][i] = fmaf(hv[0][i], w4.x, acc[j][i]);
        acc[j][i] = fmaf(hv[1][i], w4.y, acc[j][i]);
        acc[j][i] = fmaf(hv[2][i], w4.z, acc[j][i]);
        acc[j][i] = fmaf(hv[3][i], w4.w, acc[j][i]);
      }
    }
  }
}

template <int TOC, int TN, int NTPO>
__device__ __forceinline__ void store_relu(float* hout,   // + ocrow*NTPO
                                           float (&acc)[TOC][TN], int tn) {
#pragma unroll
  for (int j = 0; j < TOC; ++j) {
    float* dst = &hout[j * NTPO + tn * TN];
    if constexpr (TN == 1) {
      dst[0] = fmaxf(acc[j][0], 0.0f);
    } else if constexpr (TN == 2) {
      *(float2*)dst = make_float2(fmaxf(acc[j][0], 0.0f),
                                  fmaxf(acc[j][1], 0.0f));
    } else {
      *(float4*)dst = make_float4(fmaxf(acc[j][0], 0.0f),
                                  fmaxf(acc[j][1], 0.0f),
                                  fmaxf(acc[j][2], 0.0f),
                                  fmaxf(acc[j][3], 0.0f));
    }
  }
}

template <int TOC, int TN>
__device__ __forceinline__ void maxpool_out(float* fdst,   // feat + base + ocrow
                                            float (&acc)[TOC][TN]) {
#pragma unroll
  for (int j = 0; j < TOC; ++j) {
    float mx = 0.0f;  // relu floor
#pragma unroll
    for (int i = 0; i < TN; ++i) mx = fmaxf(mx, acc[j][i]);
    atomicMax((int*)&fdst[j], __float_as_int(mx));
  }
}

// ---------------------------------------------------------------------------
// Kernel B: one block per (b, s) sample point. 36 KB LDS -> 4 blocks/CU.
// Phase 1: 256 threads -> in-radius bitmasks (3 radii x 64 chunks).
// Phase 2: wave s walks scale-s masks, writing centered coords DIRECTLY into
// the scale-s staging buffer at ballot-prefix positions (+ first-hit pad).
// Phase 3: MLPs. Scale2's 64->96 layer runs in two 48-ch halves so hA only
// needs 48 rows; the 96->128 accumulators persist in registers (ic order
// stays 0..95 => bitwise identical).
// ---------------------------------------------------------------------------
__global__ __launch_bounds__(256) void msg_kernel(
    const float* __restrict__ pcd, const float* __restrict__ new_xyz,
    const float* __restrict__ wt,
    const float* __restrict__ b00, const float* __restrict__ b01,
    const float* __restrict__ b02, const float* __restrict__ b10,
    const float* __restrict__ b11, const float* __restrict__ b12,
    const float* __restrict__ b20, const float* __restrict__ b21,
    const float* __restrict__ b22,
    const float* __restrict__ wf, const float* __restrict__ bf,
    float* __restrict__ out) {
  __shared__ __align__(16) float hA[48 * 68];            // 13056 B
  __shared__ __align__(16) float hB[64 * 68];            // 17408 B
  __shared__ __align__(16) float c2buf[4 * 132];         //  2112 B
  __shared__ __align__(16) float c1buf[4 * 36];          //   576 B
  __shared__ __align__(16) float c0buf[4 * 20];          //   320 B
  __shared__ unsigned long long masks[3][64];            //  1536 B
  __shared__ float feat[320];                            //  1280 B

  const int bs = blockIdx.x;
  const int b = bs >> 9;
  const int tid = threadIdx.x;
  const int lane = tid & 63;
  const int wave = tid >> 6;
  const int tn = tid & 15, toc = tid >> 4;
  const float* xb = pcd + (size_t)b * NPTS * 3;

  const float cx = new_xyz[(size_t)bs * 3 + 0];
  const float cy = new_xyz[(size_t)bs * 3 + 1];
  const float cz = new_xyz[(size_t)bs * 3 + 2];

  // init: zero feat and the 4th (pad) channel row of each staging buffer
  for (int c = tid; c < 320; c += 256) feat[c] = 0.0f;
  if (tid < 132) c2buf[3 * 132 + tid] = 0.0f;
  else if (tid < 168) c1buf[3 * 36 + (tid - 132)] = 0.0f;
  else if (tid < 188) c0buf[3 * 20 + (tid - 168)] = 0.0f;

  // ---- phase 1: 16 rounds, 3 ballots each -> 192 masks ----
  const float r2a = (float)(0.1 * 0.1);
  const float r2b = (float)(0.2 * 0.2);
  const float r2c = (float)(0.4 * 0.4);
#pragma unroll 4
  for (int j = 0; j < 16; ++j) {
    int i = (j << 8) | tid;
    const float* p = xb + i * 3;
    float dx = __fsub_rn(cx, p[0]);
    float dy = __fsub_rn(cy, p[1]);
    float dz = __fsub_rn(cz, p[2]);
    float sq = __fadd_rn(__fadd_rn(__fmul_rn(dx, dx), __fmul_rn(dy, dy)),
                         __fmul_rn(dz, dz));
    unsigned long long m0 = __ballot(sq < r2a);
    unsigned long long m1 = __ballot(sq < r2b);
    unsigned long long m2 = __ballot(sq < r2c);
    if (lane == 0) {
      int c = (j << 2) | wave;
      masks[0][c] = m0; masks[1][c] = m1; masks[2][c] = m2;
    }
  }
  __syncthreads();

  // ---- phase 2: wave s -> scale-s staging buffer (centered coords) ----
  if (wave < 3) {
    const int ns   = (wave == 0) ? 16 : (wave == 1) ? 32 : 128;
    const int st   = (wave == 0) ? 20 : (wave == 1) ? 36 : 132;
    float* buf     = (wave == 0) ? c0buf : (wave == 1) ? c1buf : c2buf;
    int cnt = 0, fi = -1;
    for (int c = 0; c < 64; ++c) {
      unsigned long long m = masks[wave][c];
      if (m) {
        if (fi < 0) fi = (c << 6) | (int)__builtin_ctzll(m);
        int bit = (int)((m >> lane) & 1ull);
        int pos = cnt + (int)__popcll(m & ((1ull << lane) - 1ull));
        if (bit && pos < ns) {
          const float* p = xb + (size_t)((c << 6) | lane) * 3;
          buf[0 * st + pos] = __fsub_rn(p[0], cx);
          buf[1 * st + pos] = __fsub_rn(p[1], cy);
          buf[2 * st + pos] = __fsub_rn(p[2], cz);
        }
        cnt += (int)__popcll(m);
        if (cnt >= ns) break;
      }
    }
    if (cnt > ns) cnt = ns;
    const float* pf = xb + (size_t)fi * 3;     // center guarantees fi >= 0
    float fx = __fsub_rn(pf[0], cx);
    float fy = __fsub_rn(pf[1], cy);
    float fz = __fsub_rn(pf[2], cz);
    for (int k = cnt + lane; k < ns; k += 64) {
      buf[0 * st + k] = fx; buf[1 * st + k] = fy; buf[2 * st + k] = fz;
    }
  }
  __syncthreads();

  // ---- scale 0: ns=16, 4->32->32->64 -> feat[0:64) ----
  {
    float acc[2][1]; init_bias<2, 1>(acc, b00 + toc * 2);
    layer_acc<1, 2, 1, 20, 4>(wt + W00 + (toc * 2) * 4, c0buf, acc, tn);
    store_relu<2, 1, 18>(hB + (toc * 2) * 18, acc, tn);
  }
  __syncthreads();
  {
    float acc[2][1]; init_bias<2, 1>(acc, b01 + toc * 2);
    layer_acc<8, 2, 1, 18, 32>(wt + W01 + (toc * 2) * 32, hB, acc, tn);
    store_relu<2, 1, 18>(hA + (toc * 2) * 18, acc, tn);
  }
  __syncthreads();
  {
    float acc[4][1]; init_bias<4, 1>(acc, b02 + toc * 4);
    layer_acc<8, 4, 1, 18, 32>(wt + W02 + (toc * 4) * 32, hA, acc, tn);
    maxpool_out<4, 1>(feat + toc * 4, acc);
  }
  __syncthreads();

  // ---- scale 1: ns=32, 4->64->64->128 -> feat[64:192) ----
  {
    float acc[4][2]; init_bias<4, 2>(acc, b10 + toc * 4);
    layer_acc<1, 4, 2, 36, 4>(wt + W10 + (toc * 4) * 4, c1buf, acc, tn);
    store_relu<4, 2, 34>(hB + (toc * 4) * 34, acc, tn);
  }
  __syncthreads();
  {
    float acc[4][2]; init_bias<4, 2>(acc, b11 + toc * 4);
    layer_acc<16, 4, 2, 34, 64>(wt + W11 + (toc * 4) * 64, hB, acc, tn);
    store_relu<4, 2, 34>(hA + (toc * 4) * 34, acc, tn);
  }
  __syncthreads();
  {
    float acc[8][2]; init_bias<8, 2>(acc, b12 + toc * 8);
    layer_acc<16, 8, 2, 34, 64>(wt + W12 + (toc * 8) * 64, hA, acc, tn);
    maxpool_out<8, 2>(feat + 64 + toc * 8, acc);
  }
  __syncthreads();

  // ---- scale 2: ns=128 in 2 tiles of 64, 4->64->96->128 -> feat[192:320) --
  for (int t = 0; t < 2; ++t) {
    {
      float acc[4][4]; init_bias<4, 4>(acc, b20 + toc * 4);
      layer_acc<1, 4, 4, 132, 4>(wt + W20 + (toc * 4) * 4, c2buf + t * 64, acc, tn);
      store_relu<4, 4, 68>(hB + (toc * 4) * 68, acc, tn);
    }
    __syncthreads();
    float acc22[8][4];
    init_bias<8, 4>(acc22, b22 + toc * 8);
    // half 0: L21 out-ch [0,48) -> hA; L22 accumulates ic [0,48)
    {
      float acc[3][4]; init_bias<3, 4>(acc, b21 + toc * 3);
      layer_acc<16, 3, 4, 68, 64>(wt + W21 + (toc * 3) * 64, hB, acc, tn);
      store_relu<3, 4, 68>(hA + (toc * 3) * 68, acc, tn);
    }
    __syncthreads();
    layer_acc<12, 8, 4, 68, 96>(wt + W22 + (toc * 8) * 96 + 0, hA, acc22, tn);
    __syncthreads();
    // half 1: L21 out-ch [48,96) -> hA; L22 accumulates ic [48,96)
    {
      float acc[3][4]; init_bias<3, 4>(acc, b21 + 48 + toc * 3);
      layer_acc<16, 3, 4, 68, 64>(wt + W21 + (48 + toc * 3) * 64, hB, acc, tn);
      store_relu<3, 4, 68>(hA + (toc * 3) * 68, acc, tn);
    }
    __syncthreads();
    layer_acc<12, 8, 4, 68, 96>(wt + W22 + (toc * 8) * 96 + 48, hA, acc22, tn);
    maxpool_out<8, 4>(feat + 192 + toc * 8, acc22);
    __syncthreads();
  }

  // ---- final linear 320 -> 1 ----
  if (tid < 64) {
    float s = 0.0f;
#pragma unroll
    for (int c = 0; c < 5; ++c) s += feat[tid + c * 64] * wf[tid + c * 64];
#pragma unroll
    for (int o = 32; o > 0; o >>= 1) s += __shfl_down(s, o);
    if (tid == 0) out[bs] = s + bf[0];
  }
}

extern "C" void kernel_launch(void* const* d_in, const int* in_sizes, int n_in,
                              void* d_out, int out_size, void* d_ws, size_t ws_size,
                              hipStream_t stream) {
  const float* pcd = (const float*)d_in[0];
  float* wsf = (float*)d_ws;
  float* new_xyz = wsf;                 // 8*512*3 = 12288 floats (48 KB)
  float* wt = wsf + 12288;              // 34432 floats (transposed weights)

  prep_kernel<<<(WT_TOTAL + 255) / 256, 256, 0, stream>>>(
      (const float*)d_in[1], (const float*)d_in[3], (const float*)d_in[5],
      (const float*)d_in[7], (const float*)d_in[9], (const float*)d_in[11],
      (const float*)d_in[13], (const float*)d_in[15], (const float*)d_in[17],
      wt);

  fps_kernel<<<BATCH, 256, 0, stream>>>(pcd, new_xyz);

  msg_kernel<<<BATCH * NSAMP, 256, 0, stream>>>(
      pcd, new_xyz, wt,
      (const float*)d_in[2],  (const float*)d_in[4],  (const float*)d_in[6],
      (const float*)d_in[8],  (const float*)d_in[10], (const float*)d_in[12],
      (const float*)d_in[14], (const float*)d_in[16], (const float*)d_in[18],
      (const float*)d_in[19], (const float*)d_in[20],
      (float*)d_out);
}